// Round 15
// baseline (401.345 us; speedup 1.0000x reference)
//
#include <hip/hip_runtime.h>
#include <math.h>

#define BB 2
#define LL 2048
#define SS 2048
#define HH 8
#define EE 64
#define DD 64
#define HE (HH * EE)   // 512
// softmax scale = 1/sqrt(E) = 0.125

// ws layout (384 KB):
//   [0, 128K)     : m32  (B*H*L floats) -- BLAS-grid fp32 M_sp (bit-exact)
//   [128K, 256K)  : rank (B*H*L ints)
//   [256K, 384K)  : maxs (B*H*L floats)

typedef __attribute__((ext_vector_type(8))) short   bf16x8;   // MFMA A/B frag
typedef __attribute__((ext_vector_type(4))) float   f32x4;    // MFMA C/D frag
typedef __attribute__((ext_vector_type(8))) unsigned short u16x8;
typedef __attribute__((ext_vector_type(4))) unsigned short u16x4;

__device__ __forceinline__ unsigned short f2bf(float x) {   // fp32 -> bf16 RNE
    unsigned int u = __float_as_uint(x);
    return (unsigned short)((u + 0x7FFFu + ((u >> 16) & 1u)) >> 16);
}

__device__ __forceinline__ float rdlane(float v, int lane) { // bit-exact copy
    return __uint_as_float(
        (unsigned)__builtin_amdgcn_readlane((int)__float_as_uint(v), lane));
}

// ---------- A: BLAS-grid fp32 M_sp, VMEM + readlane broadcast (R8 exact) --
// Arithmetic sequence IDENTICAL to the verified kernel. DO NOT REORDER.
// R8 = 218us, VGPR 84, proven at ~93% of the readlane-throughput wall
// (~5cyc/readlane). All alternatives explored and dead: uniform-VMEM
// (R3 spill), 2q/lane (R9 >128 VGPR AGPR churn), LDS broadcast (R1 327us
// pipe wall), hybrids (R10/R11 lose to pure readlane). msp is DONE.
__global__ __launch_bounds__(256, 2)
void msp_blas(const float* __restrict__ Q, const float* __restrict__ K,
              float* __restrict__ m32, float* __restrict__ maxs) {
#pragma clang fp contract(off)
    const int bid = blockIdx.x;          // B*H*32 = 512
    const int lt = bid & 31, bh = bid >> 5;
    const int h = bh & 7, b = bh >> 3;
    const int t = threadIdx.x, lq = t & 63, w = t >> 6;
    const int l = lt * 64 + lq;

    float qf[64];
    const float4* qrow = (const float4*)(Q + (((size_t)b * LL + l) * HH + h) * EE);
#pragma unroll
    for (int i = 0; i < 16; i++) {
        float4 v = qrow[i];
        qf[4*i] = v.x; qf[4*i+1] = v.y; qf[4*i+2] = v.z; qf[4*i+3] = v.w;
    }

    const float* Kw = K + (((size_t)b * SS) * HH + h) * EE + (size_t)w * 512 * HE;
    const float* gld = Kw + (size_t)(lq >> 4) * HE + (lq & 15) * 4;

    float4 A0 = *(const float4*)(gld);
    float4 B0 = *(const float4*)(gld + 4 * HE);

    float mx = -1e30f;
    float blk[4];
#pragma unroll 1
    for (int lf = 0; lf < 4; ++lf) {
        float r[8];
#pragma unroll 1
        for (int i8 = 0; i8 < 16; ++i8) {
            const int kc = lf * 128 + i8 * 8;
            const int kn = (kc < 504) ? kc + 8 : 504;

            float4 A1 = *(const float4*)(gld + (size_t)kn * HE);
            float4 B1 = *(const float4*)(gld + (size_t)(kn + 4) * HE);

            float c[8];
#pragma unroll
            for (int j = 0; j < 8; ++j) c[j] = 0.f;
#pragma unroll
            for (int j = 0; j < 4; ++j) {
#pragma unroll
                for (int e4 = 0; e4 < 16; ++e4) {
                    const int ln = j * 16 + e4;
                    c[j] = fmaf(qf[4*e4+0], rdlane(A0.x, ln), c[j]);
                    c[j] = fmaf(qf[4*e4+1], rdlane(A0.y, ln), c[j]);
                    c[j] = fmaf(qf[4*e4+2], rdlane(A0.z, ln), c[j]);
                    c[j] = fmaf(qf[4*e4+3], rdlane(A0.w, ln), c[j]);
                }
            }
#pragma unroll
            for (int j = 0; j < 4; ++j) {
#pragma unroll
                for (int e4 = 0; e4 < 16; ++e4) {
                    const int ln = j * 16 + e4;
                    c[4+j] = fmaf(qf[4*e4+0], rdlane(B0.x, ln), c[4+j]);
                    c[4+j] = fmaf(qf[4*e4+1], rdlane(B0.y, ln), c[4+j]);
                    c[4+j] = fmaf(qf[4*e4+2], rdlane(B0.z, ln), c[4+j]);
                    c[4+j] = fmaf(qf[4*e4+3], rdlane(B0.w, ln), c[4+j]);
                }
            }
#pragma unroll
            for (int j = 0; j < 8; ++j) {
                mx = fmaxf(mx, c[j]);
                if (i8 == 0) r[j] = c[j];
                else         r[j] = __fadd_rn(r[j], c[j]);
            }
            A0 = A1; B0 = B1;
        }
        blk[lf] = __fadd_rn(
            __fadd_rn(__fadd_rn(r[0], r[1]), __fadd_rn(r[2], r[3])),
            __fadd_rn(__fadd_rn(r[4], r[5]), __fadd_rn(r[6], r[7])));
    }
    const float sub = __fadd_rn(__fadd_rn(blk[0], blk[1]),
                                __fadd_rn(blk[2], blk[3]));

    __shared__ float smx[4][64], ssub[4][64];
    smx[w][lq] = mx; ssub[w][lq] = sub;
    __syncthreads();
    if (w == 0) {
        const float m_all = fmaxf(fmaxf(smx[0][lq], smx[1][lq]),
                                  fmaxf(smx[2][lq], smx[3][lq]));
        const float s2048 = __fadd_rn(__fadd_rn(ssub[0][lq], ssub[1][lq]),
                                      __fadd_rn(ssub[2][lq], ssub[3][lq]));
        const float mean = __fmul_rn(s2048, 0.00048828125f);  // /2048 exact
        m32[((size_t)bh << 11) + l]  = __fsub_rn(m_all, mean);
        maxs[((size_t)bh << 11) + l] = m_all;
    }
}

// ---------- B: descending sort, ties -> lower index first (R8 exact) ------
__global__ __launch_bounds__(256)
void sort_rank(const float* __restrict__ m32, int* __restrict__ rank) {
    __shared__ unsigned int k1[2048];
    __shared__ int pay[2048];
    const int bh = blockIdx.x;
    const int t = threadIdx.x;
    for (int i = t; i < 2048; i += 256) {
        unsigned int u = __float_as_uint(m32[((size_t)bh << 11) + i]);
        u = (u & 0x80000000u) ? ~u : (u | 0x80000000u);
        k1[i] = u; pay[i] = i;
    }
    __syncthreads();
    for (int k = 2; k <= 2048; k <<= 1) {
        for (int j = k >> 1; j > 0; j >>= 1) {
            for (int i = t; i < 2048; i += 256) {
                const int ixj = i ^ j;
                if (ixj > i) {
                    unsigned int a1 = k1[i], c1 = k1[ixj];
                    int pa = pay[i], pc = pay[ixj];
                    const bool pre = (a1 > c1) || (a1 == c1 && pa < pc);
                    const bool dir = ((i & k) == 0);
                    if (dir != pre) {
                        k1[i] = c1; k1[ixj] = a1;
                        pay[i] = pc; pay[ixj] = pa;
                    }
                }
            }
            __syncthreads();
        }
    }
    for (int i = t; i < 2048; i += 256)
        rank[((size_t)bh << 11) + pay[i]] = i;   // inverse permutation
}

// ---------- C: bf16 MFMA flash, double-buffered LDS, 1 barrier/chunk ------
// Wave w owns 16 queries (rows lt*64 + w*16 .. +15) over the FULL S range.
// Per-query arithmetic IDENTICAL to the verified R8/R14 kernel.
// Structure (only change): K/VT double-buffered in LDS. Per chunk c:
//   issue chunk-c+1 global loads (regs) -> compute QK/softmax/PV from
//   buf[cur] -> f2bf+write chunk c+1 into buf[cur^1] -> ONE barrier.
// Load latency hides under MFMA+softmax; barriers per chunk 2 -> 1.
// Hazards: writes go to the buffer nobody reads this iteration; the
// end-of-iteration barrier orders write(c+1)->read(c+1) and
// read(c)->write(c, two iterations later). ldsP stays per-wave.
// R13 lesson: keep 256 threads + launch_bounds(256,2) so VGPR<=128 and
// 2 blocks/CU co-reside (92 KB LDS total <= 160 KB).
// Grid keeps R14's XCD-locality decomposition (bh = bid&15).
__global__ __launch_bounds__(256, 2)
void flash_mfma(const float* __restrict__ Q, const float* __restrict__ K,
                const float* __restrict__ V, const float* __restrict__ maxs,
                const int* __restrict__ rank, float* __restrict__ out) {
    __shared__ unsigned short ldsK[2][64 * 72];     // 18432 B (dbuf)
    __shared__ unsigned short ldsVT[2][64 * 72];    // 18432 B (dbuf, V^T)
    __shared__ unsigned short ldsP[4 * 16 * 72];    // 9216 B  (per-wave P)

    const int bid = blockIdx.x;          // 512, XCD-locality decomposition
    const int bh = bid & 15, lt = bid >> 4;
    const int h = bh & 7, b = bh >> 3;
    const int t = threadIdx.x, lane = t & 63, w = t >> 6;
    const int quad = lane >> 4, cl = lane & 15;

    const size_t kvbase = (((size_t)b * SS) * HH + h) * EE;

    // Q A-frags: A[m=cl][k=quad*8+j (+32*ef)]
    bf16x8 qa[2];
    {
        const float* qp = Q + (((size_t)b * LL + (lt * 64 + w * 16 + cl)) * HH + h) * EE
                          + quad * 8;
#pragma unroll
        for (int ef = 0; ef < 2; ++ef) {
            float4 a0 = *(const float4*)(qp + ef * 32);
            float4 a1 = *(const float4*)(qp + ef * 32 + 4);
            short* s = (short*)&qa[ef];
            s[0] = (short)f2bf(a0.x); s[1] = (short)f2bf(a0.y);
            s[2] = (short)f2bf(a0.z); s[3] = (short)f2bf(a0.w);
            s[4] = (short)f2bf(a1.x); s[5] = (short)f2bf(a1.y);
            s[6] = (short)f2bf(a1.z); s[7] = (short)f2bf(a1.w);
        }
    }

    // per-lane row constants (rows quad*4+reg)
    float negpm[4];
    int rk[4];
#pragma unroll
    for (int reg = 0; reg < 4; ++reg) {
        const int qg = lt * 64 + w * 16 + quad * 4 + reg;
        negpm[reg] = -0.125f * maxs[((size_t)bh << 11) + qg];
        rk[reg]    = rank[((size_t)bh << 11) + qg];
    }

    f32x4 accO[4];
#pragma unroll
    for (int nt = 0; nt < 4; ++nt) accO[nt] = (f32x4){0.f, 0.f, 0.f, 0.f};
    float ell[4] = {0.f, 0.f, 0.f, 0.f};

    const int pbase = w * (16 * 72);

    // staging maps (fixed per thread)
    const int krow = t >> 2, kcol = (t & 3) * 16;     // K: [s][e] pitch 72
    const int vs0 = (t & 15) * 4, vd0 = (t >> 4) * 4; // V^T: [d][s] pitch 72

    // ---- prologue: stage chunk 0 -> buf 0 ----
    {
        const float* gp = K + kvbase + (size_t)krow * HE + kcol;
        float4 f0 = ((const float4*)gp)[0];
        float4 f1 = ((const float4*)gp)[1];
        float4 f2 = ((const float4*)gp)[2];
        float4 f3 = ((const float4*)gp)[3];
        const float* gv = V + kvbase + (size_t)vs0 * HE + vd0;
        float4 v0 = *(const float4*)(gv);
        float4 v1 = *(const float4*)(gv + HE);
        float4 v2 = *(const float4*)(gv + 2 * HE);
        float4 v3 = *(const float4*)(gv + 3 * HE);
        u16x8 w0 = { f2bf(f0.x), f2bf(f0.y), f2bf(f0.z), f2bf(f0.w),
                     f2bf(f1.x), f2bf(f1.y), f2bf(f1.z), f2bf(f1.w) };
        u16x8 w1 = { f2bf(f2.x), f2bf(f2.y), f2bf(f2.z), f2bf(f2.w),
                     f2bf(f3.x), f2bf(f3.y), f2bf(f3.z), f2bf(f3.w) };
        *(u16x8*)&ldsK[0][krow * 72 + kcol]     = w0;
        *(u16x8*)&ldsK[0][krow * 72 + kcol + 8] = w1;
        u16x4 p0 = { f2bf(v0.x), f2bf(v1.x), f2bf(v2.x), f2bf(v3.x) };
        u16x4 p1 = { f2bf(v0.y), f2bf(v1.y), f2bf(v2.y), f2bf(v3.y) };
        u16x4 p2 = { f2bf(v0.z), f2bf(v1.z), f2bf(v2.z), f2bf(v3.z) };
        u16x4 p3 = { f2bf(v0.w), f2bf(v1.w), f2bf(v2.w), f2bf(v3.w) };
        *(u16x4*)&ldsVT[0][(vd0 + 0) * 72 + vs0] = p0;
        *(u16x4*)&ldsVT[0][(vd0 + 1) * 72 + vs0] = p1;
        *(u16x4*)&ldsVT[0][(vd0 + 2) * 72 + vs0] = p2;
        *(u16x4*)&ldsVT[0][(vd0 + 3) * 72 + vs0] = p3;
    }
    __syncthreads();

    int cur = 0;
#pragma unroll 1
    for (int c0 = 0; c0 < SS; c0 += 64) {
        const bool more = (c0 + 64 < SS);
        // ---- issue next-chunk loads (consumed only after compute) ----
        float4 f0, f1, f2, f3, v0, v1, v2, v3;
        if (more) {
            const float* gp = K + kvbase + (size_t)(c0 + 64 + krow) * HE + kcol;
            f0 = ((const float4*)gp)[0];
            f1 = ((const float4*)gp)[1];
            f2 = ((const float4*)gp)[2];
            f3 = ((const float4*)gp)[3];
            const float* gv = V + kvbase + (size_t)(c0 + 64 + vs0) * HE + vd0;
            v0 = *(const float4*)(gv);
            v1 = *(const float4*)(gv + HE);
            v2 = *(const float4*)(gv + 2 * HE);
            v3 = *(const float4*)(gv + 3 * HE);
        }

        // ---- QK^T: S[m=q16][n=s64] = A(Q) x B(K), B[k=e][n=s]=K[s][e] ----
        f32x4 Sc[4];
#pragma unroll
        for (int nt = 0; nt < 4; ++nt) {
            bf16x8 bk0 = *(const bf16x8*)&ldsK[cur][(nt * 16 + cl) * 72 + quad * 8];
            bf16x8 bk1 = *(const bf16x8*)&ldsK[cur][(nt * 16 + cl) * 72 + quad * 8 + 32];
            f32x4 z = (f32x4){0.f, 0.f, 0.f, 0.f};
            z = __builtin_amdgcn_mfma_f32_16x16x32_bf16(qa[0], bk0, z, 0, 0, 0);
            z = __builtin_amdgcn_mfma_f32_16x16x32_bf16(qa[1], bk1, z, 0, 0, 0);
            Sc[nt] = z;
        }

        // ---- softmax numerator + P (bf16) into A-layout LDS ----
#pragma unroll
        for (int nt = 0; nt < 4; ++nt) {
#pragma unroll
            for (int reg = 0; reg < 4; ++reg) {
                const float p = __expf(fmaf(Sc[nt][reg], 0.125f, negpm[reg]));
                ell[reg] += p;
                ldsP[pbase + (quad * 4 + reg) * 72 + nt * 16 + cl] = f2bf(p);
            }
        }

        // ---- PV: O[m=q16][n=d64] += A(P) x B(V), B[k=s][n=d]=VT[d][s] ----
        bf16x8 pa0 = *(const bf16x8*)&ldsP[pbase + cl * 72 + quad * 8];
        bf16x8 pa1 = *(const bf16x8*)&ldsP[pbase + cl * 72 + quad * 8 + 32];
#pragma unroll
        for (int nt = 0; nt < 4; ++nt) {
            bf16x8 bv0 = *(const bf16x8*)&ldsVT[cur][(nt * 16 + cl) * 72 + quad * 8];
            bf16x8 bv1 = *(const bf16x8*)&ldsVT[cur][(nt * 16 + cl) * 72 + quad * 8 + 32];
            accO[nt] = __builtin_amdgcn_mfma_f32_16x16x32_bf16(pa0, bv0, accO[nt], 0, 0, 0);
            accO[nt] = __builtin_amdgcn_mfma_f32_16x16x32_bf16(pa1, bv1, accO[nt], 0, 0, 0);
        }

        // ---- write prefetched chunk into the other buffer ----
        if (more) {
            u16x8 w0 = { f2bf(f0.x), f2bf(f0.y), f2bf(f0.z), f2bf(f0.w),
                         f2bf(f1.x), f2bf(f1.y), f2bf(f1.z), f2bf(f1.w) };
            u16x8 w1 = { f2bf(f2.x), f2bf(f2.y), f2bf(f2.z), f2bf(f2.w),
                         f2bf(f3.x), f2bf(f3.y), f2bf(f3.z), f2bf(f3.w) };
            *(u16x8*)&ldsK[cur ^ 1][krow * 72 + kcol]     = w0;
            *(u16x8*)&ldsK[cur ^ 1][krow * 72 + kcol + 8] = w1;
            u16x4 p0 = { f2bf(v0.x), f2bf(v1.x), f2bf(v2.x), f2bf(v3.x) };
            u16x4 p1 = { f2bf(v0.y), f2bf(v1.y), f2bf(v2.y), f2bf(v3.y) };
            u16x4 p2 = { f2bf(v0.z), f2bf(v1.z), f2bf(v2.z), f2bf(v3.z) };
            u16x4 p3 = { f2bf(v0.w), f2bf(v1.w), f2bf(v2.w), f2bf(v3.w) };
            *(u16x4*)&ldsVT[cur ^ 1][(vd0 + 0) * 72 + vs0] = p0;
            *(u16x4*)&ldsVT[cur ^ 1][(vd0 + 1) * 72 + vs0] = p1;
            *(u16x4*)&ldsVT[cur ^ 1][(vd0 + 2) * 72 + vs0] = p2;
            *(u16x4*)&ldsVT[cur ^ 1][(vd0 + 3) * 72 + vs0] = p3;
        }
        __syncthreads();
        cur ^= 1;
    }

    // ---- ell: reduce across the 16 lanes sharing each row (within quad) ----
#pragma unroll
    for (int reg = 0; reg < 4; ++reg) {
        float e = ell[reg];
        e += __shfl_xor(e, 1);
        e += __shfl_xor(e, 2);
        e += __shfl_xor(e, 4);
        e += __shfl_xor(e, 8);
        ell[reg] = 1.0f / e;
    }

    // ---- scatter O rows by rank ----
#pragma unroll
    for (int reg = 0; reg < 4; ++reg) {
        float* orow = out + (((size_t)b * LL + rk[reg]) * HH + h) * DD;
#pragma unroll
        for (int nt = 0; nt < 4; ++nt)
            orow[nt * 16 + cl] = accO[nt][reg] * ell[reg];
    }
}

extern "C" void kernel_launch(void* const* d_in, const int* in_sizes, int n_in,
                              void* d_out, int out_size, void* d_ws, size_t ws_size,
                              hipStream_t stream) {
    const float* Q = (const float*)d_in[0];
    const float* K = (const float*)d_in[1];
    const float* V = (const float*)d_in[2];
    float* out = (float*)d_out;

    float* m32  = (float*)d_ws;                          // 128 KB
    int*   rank = (int*)((char*)d_ws + 131072);          // 128 KB
    float* maxs = (float*)((char*)d_ws + 262144);        // 128 KB

    msp_blas<<<BB * HH * (LL / 64), 256, 0, stream>>>(Q, K, m32, maxs);
    sort_rank<<<BB * HH, 256, 0, stream>>>(m32, rank);
    flash_mfma<<<BB * HH * (LL / 64), 256, 0, stream>>>(Q, K, V, maxs, rank, out);
}

// Round 16
// 389.649 us; speedup vs baseline: 1.0300x; 1.0300x over previous
//
#include <hip/hip_runtime.h>
#include <math.h>

#define BB 2
#define LL 2048
#define SS 2048
#define HH 8
#define EE 64
#define DD 64
#define HE (HH * EE)   // 512
// softmax scale = 1/sqrt(E) = 0.125

// ws layout (384 KB):
//   [0, 128K)     : (unused -- m32 slot kept for layout stability)
//   [128K, 256K)  : rank (B*H*L ints)
//   [256K, 384K)  : maxs (B*H*L floats)
// d_out doubles as scratch for stage-A partials (512 KB of its 8 MB):
//   pmax[hf][bh][l] at out[ (hf*16+bh)*2048 + l ]
//   psum[hf][bh][l] at out[ 65536 + (hf*16+bh)*2048 + l ]
// flash_mfma fully overwrites out afterwards. (Scheme proven in R6/R7.)

typedef __attribute__((ext_vector_type(8))) short   bf16x8;   // MFMA A/B frag
typedef __attribute__((ext_vector_type(4))) float   f32x4;    // MFMA C/D frag
typedef __attribute__((ext_vector_type(8))) unsigned short u16x8;
typedef __attribute__((ext_vector_type(4))) unsigned short u16x4;

__device__ __forceinline__ unsigned short f2bf(float x) {   // fp32 -> bf16 RNE
    unsigned int u = __float_as_uint(x);
    return (unsigned short)((u + 0x7FFFu + ((u >> 16) & 1u)) >> 16);
}

__device__ __forceinline__ float rdlane(float v, int lane) { // bit-exact copy
    return __uint_as_float(
        (unsigned)__builtin_amdgcn_readlane((int)__float_as_uint(v), lane));
}

// ---------- A: M_sp partials, readlane broadcast, key-split for 4 w/SIMD --
// Arithmetic sequence IDENTICAL to the verified kernel, per 128-key blk:
// score = sequential fmaf chain e=0..63 asc, single accumulator; r[j] chain
// over i8=0..15 sequential within each blk; blk tree = exact halves;
// sub_lo = ((b0+b1)+(b2+b3)) over global blks 8hf..8hf+3, sub_hi likewise
// over 8hf+4..8hf+7; psum = fadd(sub_lo,sub_hi); sort_rank finishes
// s2048 = fadd(psum0,psum1), m_all = fmax(pmax0,pmax1). DO NOT REORDER.
// (Key-split + partial-combine decomposition bit-exact-verified in R6/R7.)
//
// R15 analysis: R8 (218us) has VALUBusy 86% -- ~70us of issue bubbles from
// readlane(~5cyc)->fmaf deps that 2 waves/SIMD can't fill. VGPR=84 supports
// 4 waves/SIMD (m69 model: waves halve at 64/128/256); the GRID was the
// limiter (512 blocks = 2/CU). This kernel: grid 1024 (hf key-halves),
// 4 blocks/CU x 4 waves = 4 waves/SIMD -> TLP fills the bubbles.
// Inner loop is R8's readlane code verbatim (wave range 256 keys, clamp 248).
__global__ __launch_bounds__(256, 2)
void msp_partial(const float* __restrict__ Q, const float* __restrict__ K,
                 float* __restrict__ pscratch) {
#pragma clang fp contract(off)
    const int bid = blockIdx.x;          // 1024 = hf*512 + bh*32 + lt
    const int hf = bid >> 9;
    const int rem = bid & 511;
    const int lt = rem & 31, bh = rem >> 5;
    const int h = bh & 7, b = bh >> 3;
    const int t = threadIdx.x, lq = t & 63, w = t >> 6;
    const int l = lt * 64 + lq;

    float qf[64];
    const float4* qrow = (const float4*)(Q + (((size_t)b * LL + l) * HH + h) * EE);
#pragma unroll
    for (int i = 0; i < 16; i++) {
        float4 v = qrow[i];
        qf[4*i] = v.x; qf[4*i+1] = v.y; qf[4*i+2] = v.z; qf[4*i+3] = v.w;
    }

    // wave w owns keys hf*1024 + [256w, 256w+256) = global blks {8hf+2w, +1}
    const float* Kw = K + (((size_t)b * SS) * HH + h) * EE
                        + (size_t)(hf * 1024 + w * 256) * HE;
    const float* gld = Kw + (size_t)(lq >> 4) * HE + (lq & 15) * 4;

    float4 A0 = *(const float4*)(gld);
    float4 B0 = *(const float4*)(gld + 4 * HE);

    float mx = -1e30f;
    float blkv[2];
#pragma unroll 1
    for (int lb = 0; lb < 2; ++lb) {
        float r[8];
#pragma unroll 1
        for (int i8 = 0; i8 < 16; ++i8) {
            const int kc = lb * 128 + i8 * 8;            // group base (0..248)
            const int kn = (kc < 248) ? kc + 8 : 248;    // next (tail: reload)

            float4 A1 = *(const float4*)(gld + (size_t)kn * HE);
            float4 B1 = *(const float4*)(gld + (size_t)(kn + 4) * HE);

            float c[8];
#pragma unroll
            for (int j = 0; j < 8; ++j) c[j] = 0.f;
#pragma unroll
            for (int j = 0; j < 4; ++j) {
#pragma unroll
                for (int e4 = 0; e4 < 16; ++e4) {
                    const int ln = j * 16 + e4;
                    c[j] = fmaf(qf[4*e4+0], rdlane(A0.x, ln), c[j]);
                    c[j] = fmaf(qf[4*e4+1], rdlane(A0.y, ln), c[j]);
                    c[j] = fmaf(qf[4*e4+2], rdlane(A0.z, ln), c[j]);
                    c[j] = fmaf(qf[4*e4+3], rdlane(A0.w, ln), c[j]);
                }
            }
#pragma unroll
            for (int j = 0; j < 4; ++j) {
#pragma unroll
                for (int e4 = 0; e4 < 16; ++e4) {
                    const int ln = j * 16 + e4;
                    c[4+j] = fmaf(qf[4*e4+0], rdlane(B0.x, ln), c[4+j]);
                    c[4+j] = fmaf(qf[4*e4+1], rdlane(B0.y, ln), c[4+j]);
                    c[4+j] = fmaf(qf[4*e4+2], rdlane(B0.z, ln), c[4+j]);
                    c[4+j] = fmaf(qf[4*e4+3], rdlane(B0.w, ln), c[4+j]);
                }
            }
#pragma unroll
            for (int j = 0; j < 8; ++j) {
                mx = fmaxf(mx, c[j]);
                if (i8 == 0) r[j] = c[j];
                else         r[j] = __fadd_rn(r[j], c[j]);
            }
            A0 = A1; B0 = B1;
        }
        blkv[lb] = __fadd_rn(
            __fadd_rn(__fadd_rn(r[0], r[1]), __fadd_rn(r[2], r[3])),
            __fadd_rn(__fadd_rn(r[4], r[5]), __fadd_rn(r[6], r[7])));
    }

    __shared__ float smx[4][64];
    __shared__ float sblk[8][64];
    smx[w][lq] = mx;
    sblk[2 * w + 0][lq] = blkv[0];     // local blk 0..7 = global 8hf..8hf+7
    sblk[2 * w + 1][lq] = blkv[1];
    __syncthreads();
    if (w == 0) {
        const float m_all = fmaxf(fmaxf(smx[0][lq], smx[1][lq]),
                                  fmaxf(smx[2][lq], smx[3][lq]));
        const float sub_lo = __fadd_rn(
            __fadd_rn(sblk[0][lq], sblk[1][lq]),
            __fadd_rn(sblk[2][lq], sblk[3][lq]));
        const float sub_hi = __fadd_rn(
            __fadd_rn(sblk[4][lq], sblk[5][lq]),
            __fadd_rn(sblk[6][lq], sblk[7][lq]));
        const float psum = __fadd_rn(sub_lo, sub_hi);
        pscratch[(((size_t)hf * 16 + bh) << 11) + l]         = m_all;   // pmax
        pscratch[65536 + (((size_t)hf * 16 + bh) << 11) + l] = psum;    // psum
    }
}

// ---------- B: combine partials + descending sort (R6-verified) -----------
__global__ __launch_bounds__(256)
void sort_rank(const float* __restrict__ pscratch, float* __restrict__ maxs,
               int* __restrict__ rank) {
    __shared__ unsigned int k1[2048];
    __shared__ int pay[2048];
    const int bh = blockIdx.x;
    const int t = threadIdx.x;
    for (int i = t; i < 2048; i += 256) {
        // finish the exact verified combine tree:
        const float pmax0 = pscratch[(((size_t)bh) << 11) + i];
        const float pmax1 = pscratch[(((size_t)16 + bh) << 11) + i];
        const float psum0 = pscratch[65536 + (((size_t)bh) << 11) + i];
        const float psum1 = pscratch[65536 + (((size_t)16 + bh) << 11) + i];
        const float m_all = fmaxf(pmax0, pmax1);
        const float s2048 = __fadd_rn(psum0, psum1);
        const float mean  = __fmul_rn(s2048, 0.00048828125f);  // /2048 exact
        const float msp   = __fsub_rn(m_all, mean);
        maxs[(((size_t)bh) << 11) + i] = m_all;
        unsigned int u = __float_as_uint(msp);
        u = (u & 0x80000000u) ? ~u : (u | 0x80000000u);
        k1[i] = u; pay[i] = i;
    }
    __syncthreads();
    for (int k = 2; k <= 2048; k <<= 1) {
        for (int j = k >> 1; j > 0; j >>= 1) {
            for (int i = t; i < 2048; i += 256) {
                const int ixj = i ^ j;
                if (ixj > i) {
                    unsigned int a1 = k1[i], c1 = k1[ixj];
                    int pa = pay[i], pc = pay[ixj];
                    const bool pre = (a1 > c1) || (a1 == c1 && pa < pc);
                    const bool dir = ((i & k) == 0);
                    if (dir != pre) {
                        k1[i] = c1; k1[ixj] = a1;
                        pay[i] = pc; pay[ixj] = pa;
                    }
                }
            }
            __syncthreads();
        }
    }
    for (int i = t; i < 2048; i += 256)
        rank[(((size_t)bh) << 11) + pay[i]] = i;   // inverse permutation
}

// ---------- C: bf16 MFMA flash, double-buffered LDS (R15, neutral-best) ---
// Wave w owns 16 queries (rows lt*64 + w*16 .. +15) over the FULL S range.
// Per-query arithmetic IDENTICAL to the verified R8/R14 kernel.
// Keeps R14's XCD-locality decomposition (bh = bid&15) and R15's dbuf.
__global__ __launch_bounds__(256, 2)
void flash_mfma(const float* __restrict__ Q, const float* __restrict__ K,
                const float* __restrict__ V, const float* __restrict__ maxs,
                const int* __restrict__ rank, float* __restrict__ out) {
    __shared__ unsigned short ldsK[2][64 * 72];     // 18432 B (dbuf)
    __shared__ unsigned short ldsVT[2][64 * 72];    // 18432 B (dbuf, V^T)
    __shared__ unsigned short ldsP[4 * 16 * 72];    // 9216 B  (per-wave P)

    const int bid = blockIdx.x;          // 512, XCD-locality decomposition
    const int bh = bid & 15, lt = bid >> 4;
    const int h = bh & 7, b = bh >> 3;
    const int t = threadIdx.x, lane = t & 63, w = t >> 6;
    const int quad = lane >> 4, cl = lane & 15;

    const size_t kvbase = (((size_t)b * SS) * HH + h) * EE;

    // Q A-frags: A[m=cl][k=quad*8+j (+32*ef)]
    bf16x8 qa[2];
    {
        const float* qp = Q + (((size_t)b * LL + (lt * 64 + w * 16 + cl)) * HH + h) * EE
                          + quad * 8;
#pragma unroll
        for (int ef = 0; ef < 2; ++ef) {
            float4 a0 = *(const float4*)(qp + ef * 32);
            float4 a1 = *(const float4*)(qp + ef * 32 + 4);
            short* s = (short*)&qa[ef];
            s[0] = (short)f2bf(a0.x); s[1] = (short)f2bf(a0.y);
            s[2] = (short)f2bf(a0.z); s[3] = (short)f2bf(a0.w);
            s[4] = (short)f2bf(a1.x); s[5] = (short)f2bf(a1.y);
            s[6] = (short)f2bf(a1.z); s[7] = (short)f2bf(a1.w);
        }
    }

    // per-lane row constants (rows quad*4+reg)
    float negpm[4];
    int rk[4];
#pragma unroll
    for (int reg = 0; reg < 4; ++reg) {
        const int qg = lt * 64 + w * 16 + quad * 4 + reg;
        negpm[reg] = -0.125f * maxs[((size_t)bh << 11) + qg];
        rk[reg]    = rank[((size_t)bh << 11) + qg];
    }

    f32x4 accO[4];
#pragma unroll
    for (int nt = 0; nt < 4; ++nt) accO[nt] = (f32x4){0.f, 0.f, 0.f, 0.f};
    float ell[4] = {0.f, 0.f, 0.f, 0.f};

    const int pbase = w * (16 * 72);

    // staging maps (fixed per thread)
    const int krow = t >> 2, kcol = (t & 3) * 16;     // K: [s][e] pitch 72
    const int vs0 = (t & 15) * 4, vd0 = (t >> 4) * 4; // V^T: [d][s] pitch 72

    // ---- prologue: stage chunk 0 -> buf 0 ----
    {
        const float* gp = K + kvbase + (size_t)krow * HE + kcol;
        float4 f0 = ((const float4*)gp)[0];
        float4 f1 = ((const float4*)gp)[1];
        float4 f2 = ((const float4*)gp)[2];
        float4 f3 = ((const float4*)gp)[3];
        const float* gv = V + kvbase + (size_t)vs0 * HE + vd0;
        float4 v0 = *(const float4*)(gv);
        float4 v1 = *(const float4*)(gv + HE);
        float4 v2 = *(const float4*)(gv + 2 * HE);
        float4 v3 = *(const float4*)(gv + 3 * HE);
        u16x8 w0 = { f2bf(f0.x), f2bf(f0.y), f2bf(f0.z), f2bf(f0.w),
                     f2bf(f1.x), f2bf(f1.y), f2bf(f1.z), f2bf(f1.w) };
        u16x8 w1 = { f2bf(f2.x), f2bf(f2.y), f2bf(f2.z), f2bf(f2.w),
                     f2bf(f3.x), f2bf(f3.y), f2bf(f3.z), f2bf(f3.w) };
        *(u16x8*)&ldsK[0][krow * 72 + kcol]     = w0;
        *(u16x8*)&ldsK[0][krow * 72 + kcol + 8] = w1;
        u16x4 p0 = { f2bf(v0.x), f2bf(v1.x), f2bf(v2.x), f2bf(v3.x) };
        u16x4 p1 = { f2bf(v0.y), f2bf(v1.y), f2bf(v2.y), f2bf(v3.y) };
        u16x4 p2 = { f2bf(v0.z), f2bf(v1.z), f2bf(v2.z), f2bf(v3.z) };
        u16x4 p3 = { f2bf(v0.w), f2bf(v1.w), f2bf(v2.w), f2bf(v3.w) };
        *(u16x4*)&ldsVT[0][(vd0 + 0) * 72 + vs0] = p0;
        *(u16x4*)&ldsVT[0][(vd0 + 1) * 72 + vs0] = p1;
        *(u16x4*)&ldsVT[0][(vd0 + 2) * 72 + vs0] = p2;
        *(u16x4*)&ldsVT[0][(vd0 + 3) * 72 + vs0] = p3;
    }
    __syncthreads();

    int cur = 0;
#pragma unroll 1
    for (int c0 = 0; c0 < SS; c0 += 64) {
        const bool more = (c0 + 64 < SS);
        // ---- issue next-chunk loads (consumed only after compute) ----
        float4 f0, f1, f2, f3, v0, v1, v2, v3;
        if (more) {
            const float* gp = K + kvbase + (size_t)(c0 + 64 + krow) * HE + kcol;
            f0 = ((const float4*)gp)[0];
            f1 = ((const float4*)gp)[1];
            f2 = ((const float4*)gp)[2];
            f3 = ((const float4*)gp)[3];
            const float* gv = V + kvbase + (size_t)(c0 + 64 + vs0) * HE + vd0;
            v0 = *(const float4*)(gv);
            v1 = *(const float4*)(gv + HE);
            v2 = *(const float4*)(gv + 2 * HE);
            v3 = *(const float4*)(gv + 3 * HE);
        }

        // ---- QK^T: S[m=q16][n=s64] = A(Q) x B(K), B[k=e][n=s]=K[s][e] ----
        f32x4 Sc[4];
#pragma unroll
        for (int nt = 0; nt < 4; ++nt) {
            bf16x8 bk0 = *(const bf16x8*)&ldsK[cur][(nt * 16 + cl) * 72 + quad * 8];
            bf16x8 bk1 = *(const bf16x8*)&ldsK[cur][(nt * 16 + cl) * 72 + quad * 8 + 32];
            f32x4 z = (f32x4){0.f, 0.f, 0.f, 0.f};
            z = __builtin_amdgcn_mfma_f32_16x16x32_bf16(qa[0], bk0, z, 0, 0, 0);
            z = __builtin_amdgcn_mfma_f32_16x16x32_bf16(qa[1], bk1, z, 0, 0, 0);
            Sc[nt] = z;
        }

        // ---- softmax numerator + P (bf16) into A-layout LDS ----
#pragma unroll
        for (int nt = 0; nt < 4; ++nt) {
#pragma unroll
            for (int reg = 0; reg < 4; ++reg) {
                const float p = __expf(fmaf(Sc[nt][reg], 0.125f, negpm[reg]));
                ell[reg] += p;
                ldsP[pbase + (quad * 4 + reg) * 72 + nt * 16 + cl] = f2bf(p);
            }
        }

        // ---- PV: O[m=q16][n=d64] += A(P) x B(V), B[k=s][n=d]=VT[d][s] ----
        bf16x8 pa0 = *(const bf16x8*)&ldsP[pbase + cl * 72 + quad * 8];
        bf16x8 pa1 = *(const bf16x8*)&ldsP[pbase + cl * 72 + quad * 8 + 32];
#pragma unroll
        for (int nt = 0; nt < 4; ++nt) {
            bf16x8 bv0 = *(const bf16x8*)&ldsVT[cur][(nt * 16 + cl) * 72 + quad * 8];
            bf16x8 bv1 = *(const bf16x8*)&ldsVT[cur][(nt * 16 + cl) * 72 + quad * 8 + 32];
            accO[nt] = __builtin_amdgcn_mfma_f32_16x16x32_bf16(pa0, bv0, accO[nt], 0, 0, 0);
            accO[nt] = __builtin_amdgcn_mfma_f32_16x16x32_bf16(pa1, bv1, accO[nt], 0, 0, 0);
        }

        // ---- write prefetched chunk into the other buffer ----
        if (more) {
            u16x8 w0 = { f2bf(f0.x), f2bf(f0.y), f2bf(f0.z), f2bf(f0.w),
                         f2bf(f1.x), f2bf(f1.y), f2bf(f1.z), f2bf(f1.w) };
            u16x8 w1 = { f2bf(f2.x), f2bf(f2.y), f2bf(f2.z), f2bf(f2.w),
                         f2bf(f3.x), f2bf(f3.y), f2bf(f3.z), f2bf(f3.w) };
            *(u16x8*)&ldsK[cur ^ 1][krow * 72 + kcol]     = w0;
            *(u16x8*)&ldsK[cur ^ 1][krow * 72 + kcol + 8] = w1;
            u16x4 p0 = { f2bf(v0.x), f2bf(v1.x), f2bf(v2.x), f2bf(v3.x) };
            u16x4 p1 = { f2bf(v0.y), f2bf(v1.y), f2bf(v2.y), f2bf(v3.y) };
            u16x4 p2 = { f2bf(v0.z), f2bf(v1.z), f2bf(v2.z), f2bf(v3.z) };
            u16x4 p3 = { f2bf(v0.w), f2bf(v1.w), f2bf(v2.w), f2bf(v3.w) };
            *(u16x4*)&ldsVT[cur ^ 1][(vd0 + 0) * 72 + vs0] = p0;
            *(u16x4*)&ldsVT[cur ^ 1][(vd0 + 1) * 72 + vs0] = p1;
            *(u16x4*)&ldsVT[cur ^ 1][(vd0 + 2) * 72 + vs0] = p2;
            *(u16x4*)&ldsVT[cur ^ 1][(vd0 + 3) * 72 + vs0] = p3;
        }
        __syncthreads();
        cur ^= 1;
    }

    // ---- ell: reduce across the 16 lanes sharing each row (within quad) ----
#pragma unroll
    for (int reg = 0; reg < 4; ++reg) {
        float e = ell[reg];
        e += __shfl_xor(e, 1);
        e += __shfl_xor(e, 2);
        e += __shfl_xor(e, 4);
        e += __shfl_xor(e, 8);
        ell[reg] = 1.0f / e;
    }

    // ---- scatter O rows by rank ----
#pragma unroll
    for (int reg = 0; reg < 4; ++reg) {
        float* orow = out + (((size_t)b * LL + rk[reg]) * HH + h) * DD;
#pragma unroll
        for (int nt = 0; nt < 4; ++nt)
            orow[nt * 16 + cl] = accO[nt][reg] * ell[reg];
    }
}

extern "C" void kernel_launch(void* const* d_in, const int* in_sizes, int n_in,
                              void* d_out, int out_size, void* d_ws, size_t ws_size,
                              hipStream_t stream) {
    const float* Q = (const float*)d_in[0];
    const float* K = (const float*)d_in[1];
    const float* V = (const float*)d_in[2];
    float* out = (float*)d_out;

    int*   rank = (int*)((char*)d_ws + 131072);          // 128 KB
    float* maxs = (float*)((char*)d_ws + 262144);        // 128 KB

    // stage-A partials live in the first 512 KB of d_out (overwritten later)
    msp_partial<<<2 * BB * HH * (LL / 64), 256, 0, stream>>>(Q, K, out);
    sort_rank<<<BB * HH, 256, 0, stream>>>(out, maxs, rank);
    flash_mfma<<<BB * HH * (LL / 64), 256, 0, stream>>>(Q, K, V, maxs, rank, out);
}

// Round 17
// 352.808 us; speedup vs baseline: 1.1376x; 1.1044x over previous
//
#include <hip/hip_runtime.h>
#include <math.h>

#define BB 2
#define LL 2048
#define SS 2048
#define HH 8
#define EE 64
#define DD 64
#define HE (HH * EE)   // 512
// softmax scale = 1/sqrt(E) = 0.125

// ws layout (384 KB):
//   [0, 128K)     : (unused)
//   [128K, 256K)  : rank (B*H*L ints)
//   [256K, 384K)  : maxs (B*H*L floats)
// d_out doubles as scratch for stage-A partials (1 MB of its 8.4 MB):
//   pmax[hf][bh][l] at out[ (hf*16+bh)*2048 + l ]          (hf = 0..3)
//   psum[hf][bh][l] at out[ 131072 + (hf*16+bh)*2048 + l ]
// flash_mfma fully overwrites out afterwards. (Scheme proven R6/R7/R16.)

typedef __attribute__((ext_vector_type(8))) short   bf16x8;   // MFMA A/B frag
typedef __attribute__((ext_vector_type(4))) float   f32x4;    // MFMA C/D frag
typedef __attribute__((ext_vector_type(8))) unsigned short u16x8;
typedef __attribute__((ext_vector_type(4))) unsigned short u16x4;

__device__ __forceinline__ unsigned short f2bf(float x) {   // fp32 -> bf16 RNE
    unsigned int u = __float_as_uint(x);
    return (unsigned short)((u + 0x7FFFu + ((u >> 16) & 1u)) >> 16);
}

__device__ __forceinline__ float rdlane(float v, int lane) { // bit-exact copy
    return __uint_as_float(
        (unsigned)__builtin_amdgcn_readlane((int)__float_as_uint(v), lane));
}

// ---------- A: M_sp partials, readlane broadcast, 4-way key-split ---------
// Arithmetic sequence IDENTICAL to the verified kernel, per 128-key blk:
// score = sequential fmaf chain e=0..63 asc, single accumulator; r[j] chain
// over i8=0..15 sequential within the blk; blk tree = exact halves over
// r[0..7]. Block combine: sub_hf = ((blk[4hf]+blk[4hf+1])+(blk[4hf+2]+
// blk[4hf+3])) -- VERBATIM the verified in-wave sub tree (wave w holds
// blk[4hf+w]). sort_rank finishes s2048 = ((sub0+sub1)+(sub2+sub3)) --
// verbatim the verified top tree -- and m_all = fmax over 4 pmax
// (order-free). DO NOT REORDER. (Decomposition class verified R6/R7/R16.)
//
// R16 analysis: 2-way split -> 4 waves/SIMD, msp 218->207, VALUBusy 85%.
// VGPR=84 allows floor(512/84)=6 waves/SIMD; grid again the limiter.
// This kernel: 4-way split, grid 2048 = 8 blocks/CU -> 6 waves/SIMD
// (VGPR-capped) -> more readlane bubbles filled by TLP.
__global__ __launch_bounds__(256, 2)
void msp_partial(const float* __restrict__ Q, const float* __restrict__ K,
                 float* __restrict__ pscratch) {
#pragma clang fp contract(off)
    const int bid = blockIdx.x;          // 2048 = hf*512 + bh*32 + lt
    const int hf = bid >> 9;             // key quarter 0..3
    const int rem = bid & 511;
    const int lt = rem & 31, bh = rem >> 5;
    const int h = bh & 7, b = bh >> 3;
    const int t = threadIdx.x, lq = t & 63, w = t >> 6;
    const int l = lt * 64 + lq;

    float qf[64];
    const float4* qrow = (const float4*)(Q + (((size_t)b * LL + l) * HH + h) * EE);
#pragma unroll
    for (int i = 0; i < 16; i++) {
        float4 v = qrow[i];
        qf[4*i] = v.x; qf[4*i+1] = v.y; qf[4*i+2] = v.z; qf[4*i+3] = v.w;
    }

    // wave w owns keys hf*512 + [128w, 128w+128) = global blk 4hf+w
    const float* Kw = K + (((size_t)b * SS) * HH + h) * EE
                        + (size_t)(hf * 512 + w * 128) * HE;
    const float* gld = Kw + (size_t)(lq >> 4) * HE + (lq & 15) * 4;

    float4 A0 = *(const float4*)(gld);
    float4 B0 = *(const float4*)(gld + 4 * HE);

    float mx = -1e30f;
    float r[8];
#pragma unroll 1
    for (int i8 = 0; i8 < 16; ++i8) {
        const int kc = i8 * 8;                       // group base (0..120)
        const int kn = (kc < 120) ? kc + 8 : 120;    // next (tail: reload)

        float4 A1 = *(const float4*)(gld + (size_t)kn * HE);
        float4 B1 = *(const float4*)(gld + (size_t)(kn + 4) * HE);

        float c[8];
#pragma unroll
        for (int j = 0; j < 8; ++j) c[j] = 0.f;
#pragma unroll
        for (int j = 0; j < 4; ++j) {
#pragma unroll
            for (int e4 = 0; e4 < 16; ++e4) {
                const int ln = j * 16 + e4;
                c[j] = fmaf(qf[4*e4+0], rdlane(A0.x, ln), c[j]);
                c[j] = fmaf(qf[4*e4+1], rdlane(A0.y, ln), c[j]);
                c[j] = fmaf(qf[4*e4+2], rdlane(A0.z, ln), c[j]);
                c[j] = fmaf(qf[4*e4+3], rdlane(A0.w, ln), c[j]);
            }
        }
#pragma unroll
        for (int j = 0; j < 4; ++j) {
#pragma unroll
            for (int e4 = 0; e4 < 16; ++e4) {
                const int ln = j * 16 + e4;
                c[4+j] = fmaf(qf[4*e4+0], rdlane(B0.x, ln), c[4+j]);
                c[4+j] = fmaf(qf[4*e4+1], rdlane(B0.y, ln), c[4+j]);
                c[4+j] = fmaf(qf[4*e4+2], rdlane(B0.z, ln), c[4+j]);
                c[4+j] = fmaf(qf[4*e4+3], rdlane(B0.w, ln), c[4+j]);
            }
        }
#pragma unroll
        for (int j = 0; j < 8; ++j) {
            mx = fmaxf(mx, c[j]);
            if (i8 == 0) r[j] = c[j];
            else         r[j] = __fadd_rn(r[j], c[j]);
        }
        A0 = A1; B0 = B1;
    }
    const float blkv = __fadd_rn(
        __fadd_rn(__fadd_rn(r[0], r[1]), __fadd_rn(r[2], r[3])),
        __fadd_rn(__fadd_rn(r[4], r[5]), __fadd_rn(r[6], r[7])));

    __shared__ float smx[4][64], sblk[4][64];
    smx[w][lq] = mx; sblk[w][lq] = blkv;
    __syncthreads();
    if (w == 0) {
        const float m_all = fmaxf(fmaxf(smx[0][lq], smx[1][lq]),
                                  fmaxf(smx[2][lq], smx[3][lq]));
        // sub_hf = ((blk[4hf]+blk[4hf+1])+(blk[4hf+2]+blk[4hf+3])) -- the
        // verified in-wave tree over this quarter's 4 blks.
        const float sub = __fadd_rn(
            __fadd_rn(sblk[0][lq], sblk[1][lq]),
            __fadd_rn(sblk[2][lq], sblk[3][lq]));
        pscratch[(((size_t)hf * 16 + bh) << 11) + l]          = m_all;  // pmax
        pscratch[131072 + (((size_t)hf * 16 + bh) << 11) + l] = sub;    // psum
    }
}

// ---------- B: combine 4 partials + descending sort (1024 thr) ------------
// s2048 = ((sub0+sub1)+(sub2+sub3)) -- verbatim verified top tree.
// 1024-thread bitonic (same algorithm, stride 1024) ran correct in R12.
__global__ __launch_bounds__(1024)
void sort_rank(const float* __restrict__ pscratch, float* __restrict__ maxs,
               int* __restrict__ rank) {
    __shared__ unsigned int k1[2048];
    __shared__ int pay[2048];
    const int bh = blockIdx.x;
    const int t = threadIdx.x;
    for (int i = t; i < 2048; i += 1024) {
        const float p0 = pscratch[(((size_t)(0 * 16 + bh)) << 11) + i];
        const float p1 = pscratch[(((size_t)(1 * 16 + bh)) << 11) + i];
        const float p2 = pscratch[(((size_t)(2 * 16 + bh)) << 11) + i];
        const float p3 = pscratch[(((size_t)(3 * 16 + bh)) << 11) + i];
        const float s0 = pscratch[131072 + (((size_t)(0 * 16 + bh)) << 11) + i];
        const float s1 = pscratch[131072 + (((size_t)(1 * 16 + bh)) << 11) + i];
        const float s2 = pscratch[131072 + (((size_t)(2 * 16 + bh)) << 11) + i];
        const float s3 = pscratch[131072 + (((size_t)(3 * 16 + bh)) << 11) + i];
        const float m_all = fmaxf(fmaxf(p0, p1), fmaxf(p2, p3));
        const float s2048 = __fadd_rn(__fadd_rn(s0, s1), __fadd_rn(s2, s3));
        const float mean  = __fmul_rn(s2048, 0.00048828125f);  // /2048 exact
        const float msp   = __fsub_rn(m_all, mean);
        maxs[(((size_t)bh) << 11) + i] = m_all;
        unsigned int u = __float_as_uint(msp);
        u = (u & 0x80000000u) ? ~u : (u | 0x80000000u);
        k1[i] = u; pay[i] = i;
    }
    __syncthreads();
    for (int k = 2; k <= 2048; k <<= 1) {
        for (int j = k >> 1; j > 0; j >>= 1) {
            for (int i = t; i < 2048; i += 1024) {
                const int ixj = i ^ j;
                if (ixj > i) {
                    unsigned int a1 = k1[i], c1 = k1[ixj];
                    int pa = pay[i], pc = pay[ixj];
                    const bool pre = (a1 > c1) || (a1 == c1 && pa < pc);
                    const bool dir = ((i & k) == 0);
                    if (dir != pre) {
                        k1[i] = c1; k1[ixj] = a1;
                        pay[i] = pc; pay[ixj] = pa;
                    }
                }
            }
            __syncthreads();
        }
    }
    for (int i = t; i < 2048; i += 1024)
        rank[(((size_t)bh) << 11) + pay[i]] = i;   // inverse permutation
}

// ---------- C: bf16 MFMA flash, double-buffered LDS (R15/R16 best) --------
// Wave w owns 16 queries (rows lt*64 + w*16 .. +15) over the FULL S range.
// Per-query arithmetic IDENTICAL to the verified R8/R14 kernel.
// Keeps R14's XCD-locality decomposition (bh = bid&15) and R15's dbuf.
__global__ __launch_bounds__(256, 2)
void flash_mfma(const float* __restrict__ Q, const float* __restrict__ K,
                const float* __restrict__ V, const float* __restrict__ maxs,
                const int* __restrict__ rank, float* __restrict__ out) {
    __shared__ unsigned short ldsK[2][64 * 72];     // 18432 B (dbuf)
    __shared__ unsigned short ldsVT[2][64 * 72];    // 18432 B (dbuf, V^T)
    __shared__ unsigned short ldsP[4 * 16 * 72];    // 9216 B  (per-wave P)

    const int bid = blockIdx.x;          // 512, XCD-locality decomposition
    const int bh = bid & 15, lt = bid >> 4;
    const int h = bh & 7, b = bh >> 3;
    const int t = threadIdx.x, lane = t & 63, w = t >> 6;
    const int quad = lane >> 4, cl = lane & 15;

    const size_t kvbase = (((size_t)b * SS) * HH + h) * EE;

    // Q A-frags: A[m=cl][k=quad*8+j (+32*ef)]
    bf16x8 qa[2];
    {
        const float* qp = Q + (((size_t)b * LL + (lt * 64 + w * 16 + cl)) * HH + h) * EE
                          + quad * 8;
#pragma unroll
        for (int ef = 0; ef < 2; ++ef) {
            float4 a0 = *(const float4*)(qp + ef * 32);
            float4 a1 = *(const float4*)(qp + ef * 32 + 4);
            short* s = (short*)&qa[ef];
            s[0] = (short)f2bf(a0.x); s[1] = (short)f2bf(a0.y);
            s[2] = (short)f2bf(a0.z); s[3] = (short)f2bf(a0.w);
            s[4] = (short)f2bf(a1.x); s[5] = (short)f2bf(a1.y);
            s[6] = (short)f2bf(a1.z); s[7] = (short)f2bf(a1.w);
        }
    }

    // per-lane row constants (rows quad*4+reg)
    float negpm[4];
    int rk[4];
#pragma unroll
    for (int reg = 0; reg < 4; ++reg) {
        const int qg = lt * 64 + w * 16 + quad * 4 + reg;
        negpm[reg] = -0.125f * maxs[((size_t)bh << 11) + qg];
        rk[reg]    = rank[((size_t)bh << 11) + qg];
    }

    f32x4 accO[4];
#pragma unroll
    for (int nt = 0; nt < 4; ++nt) accO[nt] = (f32x4){0.f, 0.f, 0.f, 0.f};
    float ell[4] = {0.f, 0.f, 0.f, 0.f};

    const int pbase = w * (16 * 72);

    // staging maps (fixed per thread)
    const int krow = t >> 2, kcol = (t & 3) * 16;     // K: [s][e] pitch 72
    const int vs0 = (t & 15) * 4, vd0 = (t >> 4) * 4; // V^T: [d][s] pitch 72

    // ---- prologue: stage chunk 0 -> buf 0 ----
    {
        const float* gp = K + kvbase + (size_t)krow * HE + kcol;
        float4 f0 = ((const float4*)gp)[0];
        float4 f1 = ((const float4*)gp)[1];
        float4 f2 = ((const float4*)gp)[2];
        float4 f3 = ((const float4*)gp)[3];
        const float* gv = V + kvbase + (size_t)vs0 * HE + vd0;
        float4 v0 = *(const float4*)(gv);
        float4 v1 = *(const float4*)(gv + HE);
        float4 v2 = *(const float4*)(gv + 2 * HE);
        float4 v3 = *(const float4*)(gv + 3 * HE);
        u16x8 w0 = { f2bf(f0.x), f2bf(f0.y), f2bf(f0.z), f2bf(f0.w),
                     f2bf(f1.x), f2bf(f1.y), f2bf(f1.z), f2bf(f1.w) };
        u16x8 w1 = { f2bf(f2.x), f2bf(f2.y), f2bf(f2.z), f2bf(f2.w),
                     f2bf(f3.x), f2bf(f3.y), f2bf(f3.z), f2bf(f3.w) };
        *(u16x8*)&ldsK[0][krow * 72 + kcol]     = w0;
        *(u16x8*)&ldsK[0][krow * 72 + kcol + 8] = w1;
        u16x4 p0 = { f2bf(v0.x), f2bf(v1.x), f2bf(v2.x), f2bf(v3.x) };
        u16x4 p1 = { f2bf(v0.y), f2bf(v1.y), f2bf(v2.y), f2bf(v3.y) };
        u16x4 p2 = { f2bf(v0.z), f2bf(v1.z), f2bf(v2.z), f2bf(v3.z) };
        u16x4 p3 = { f2bf(v0.w), f2bf(v1.w), f2bf(v2.w), f2bf(v3.w) };
        *(u16x4*)&ldsVT[0][(vd0 + 0) * 72 + vs0] = p0;
        *(u16x4*)&ldsVT[0][(vd0 + 1) * 72 + vs0] = p1;
        *(u16x4*)&ldsVT[0][(vd0 + 2) * 72 + vs0] = p2;
        *(u16x4*)&ldsVT[0][(vd0 + 3) * 72 + vs0] = p3;
    }
    __syncthreads();

    int cur = 0;
#pragma unroll 1
    for (int c0 = 0; c0 < SS; c0 += 64) {
        const bool more = (c0 + 64 < SS);
        // ---- issue next-chunk loads (consumed only after compute) ----
        float4 f0, f1, f2, f3, v0, v1, v2, v3;
        if (more) {
            const float* gp = K + kvbase + (size_t)(c0 + 64 + krow) * HE + kcol;
            f0 = ((const float4*)gp)[0];
            f1 = ((const float4*)gp)[1];
            f2 = ((const float4*)gp)[2];
            f3 = ((const float4*)gp)[3];
            const float* gv = V + kvbase + (size_t)(c0 + 64 + vs0) * HE + vd0;
            v0 = *(const float4*)(gv);
            v1 = *(const float4*)(gv + HE);
            v2 = *(const float4*)(gv + 2 * HE);
            v3 = *(const float4*)(gv + 3 * HE);
        }

        // ---- QK^T: S[m=q16][n=s64] = A(Q) x B(K), B[k=e][n=s]=K[s][e] ----
        f32x4 Sc[4];
#pragma unroll
        for (int nt = 0; nt < 4; ++nt) {
            bf16x8 bk0 = *(const bf16x8*)&ldsK[cur][(nt * 16 + cl) * 72 + quad * 8];
            bf16x8 bk1 = *(const bf16x8*)&ldsK[cur][(nt * 16 + cl) * 72 + quad * 8 + 32];
            f32x4 z = (f32x4){0.f, 0.f, 0.f, 0.f};
            z = __builtin_amdgcn_mfma_f32_16x16x32_bf16(qa[0], bk0, z, 0, 0, 0);
            z = __builtin_amdgcn_mfma_f32_16x16x32_bf16(qa[1], bk1, z, 0, 0, 0);
            Sc[nt] = z;
        }

        // ---- softmax numerator + P (bf16) into A-layout LDS ----
#pragma unroll
        for (int nt = 0; nt < 4; ++nt) {
#pragma unroll
            for (int reg = 0; reg < 4; ++reg) {
                const float p = __expf(fmaf(Sc[nt][reg], 0.125f, negpm[reg]));
                ell[reg] += p;
                ldsP[pbase + (quad * 4 + reg) * 72 + nt * 16 + cl] = f2bf(p);
            }
        }

        // ---- PV: O[m=q16][n=d64] += A(P) x B(V), B[k=s][n=d]=VT[d][s] ----
        bf16x8 pa0 = *(const bf16x8*)&ldsP[pbase + cl * 72 + quad * 8];
        bf16x8 pa1 = *(const bf16x8*)&ldsP[pbase + cl * 72 + quad * 8 + 32];
#pragma unroll
        for (int nt = 0; nt < 4; ++nt) {
            bf16x8 bv0 = *(const bf16x8*)&ldsVT[cur][(nt * 16 + cl) * 72 + quad * 8];
            bf16x8 bv1 = *(const bf16x8*)&ldsVT[cur][(nt * 16 + cl) * 72 + quad * 8 + 32];
            accO[nt] = __builtin_amdgcn_mfma_f32_16x16x32_bf16(pa0, bv0, accO[nt], 0, 0, 0);
            accO[nt] = __builtin_amdgcn_mfma_f32_16x16x32_bf16(pa1, bv1, accO[nt], 0, 0, 0);
        }

        // ---- write prefetched chunk into the other buffer ----
        if (more) {
            u16x8 w0 = { f2bf(f0.x), f2bf(f0.y), f2bf(f0.z), f2bf(f0.w),
                         f2bf(f1.x), f2bf(f1.y), f2bf(f1.z), f2bf(f1.w) };
            u16x8 w1 = { f2bf(f2.x), f2bf(f2.y), f2bf(f2.z), f2bf(f2.w),
                         f2bf(f3.x), f2bf(f3.y), f2bf(f3.z), f2bf(f3.w) };
            *(u16x8*)&ldsK[cur ^ 1][krow * 72 + kcol]     = w0;
            *(u16x8*)&ldsK[cur ^ 1][krow * 72 + kcol + 8] = w1;
            u16x4 p0 = { f2bf(v0.x), f2bf(v1.x), f2bf(v2.x), f2bf(v3.x) };
            u16x4 p1 = { f2bf(v0.y), f2bf(v1.y), f2bf(v2.y), f2bf(v3.y) };
            u16x4 p2 = { f2bf(v0.z), f2bf(v1.z), f2bf(v2.z), f2bf(v3.z) };
            u16x4 p3 = { f2bf(v0.w), f2bf(v1.w), f2bf(v2.w), f2bf(v3.w) };
            *(u16x4*)&ldsVT[cur ^ 1][(vd0 + 0) * 72 + vs0] = p0;
            *(u16x4*)&ldsVT[cur ^ 1][(vd0 + 1) * 72 + vs0] = p1;
            *(u16x4*)&ldsVT[cur ^ 1][(vd0 + 2) * 72 + vs0] = p2;
            *(u16x4*)&ldsVT[cur ^ 1][(vd0 + 3) * 72 + vs0] = p3;
        }
        __syncthreads();
        cur ^= 1;
    }

    // ---- ell: reduce across the 16 lanes sharing each row (within quad) ----
#pragma unroll
    for (int reg = 0; reg < 4; ++reg) {
        float e = ell[reg];
        e += __shfl_xor(e, 1);
        e += __shfl_xor(e, 2);
        e += __shfl_xor(e, 4);
        e += __shfl_xor(e, 8);
        ell[reg] = 1.0f / e;
    }

    // ---- scatter O rows by rank ----
#pragma unroll
    for (int reg = 0; reg < 4; ++reg) {
        float* orow = out + (((size_t)b * LL + rk[reg]) * HH + h) * DD;
#pragma unroll
        for (int nt = 0; nt < 4; ++nt)
            orow[nt * 16 + cl] = accO[nt][reg] * ell[reg];
    }
}

extern "C" void kernel_launch(void* const* d_in, const int* in_sizes, int n_in,
                              void* d_out, int out_size, void* d_ws, size_t ws_size,
                              hipStream_t stream) {
    const float* Q = (const float*)d_in[0];
    const float* K = (const float*)d_in[1];
    const float* V = (const float*)d_in[2];
    float* out = (float*)d_out;

    int*   rank = (int*)((char*)d_ws + 131072);          // 128 KB
    float* maxs = (float*)((char*)d_ws + 262144);        // 128 KB

    // stage-A partials live in the first 1 MB of d_out (overwritten later)
    msp_partial<<<4 * BB * HH * (LL / 64), 256, 0, stream>>>(Q, K, out);
    sort_rank<<<BB * HH, 1024, 0, stream>>>(out, maxs, rank);
    flash_mfma<<<BB * HH * (LL / 64), 256, 0, stream>>>(Q, K, V, maxs, rank, out);
}